// Round 6
// baseline (331.260 us; speedup 1.0000x reference)
//
#include <hip/hip_runtime.h>
#include <math.h>

// Bahdanau attention, B=32, T=2048, D=512, U=512, fp32 in/out.
// Round 13: r12 design with the GRID BUG fixed. M = B*T = 65536 rows ->
// 1024 m-tiles of 64 rows x 4 u-tiles = 4096 blocks (r12 launched 1024:
// only batches 0-7 were computed; batches 8-31 had zero scores -> uniform
// softmax -> absmax 8.7e-2). XCD chunk = 4096/8 = 512. All per-lane
// staging/frag/epilogue formulas unchanged (re-verified by lane-level
// simulation in the r12 audit).
// Score: 64m x 128u tiles, 256 thr / 4 waves, 33KB LDS, launch_bounds(256,4)
// -> 4 blocks/CU (16 waves/CU); simple __syncthreads dbuf loop; cross-block
// TLP hides the barrier drain (m114 mechanism).

#define B_ 32
#define T_ 2048
#define D_ 512
#define U_ 512
#define M_ (B_ * T_)

typedef _Float16 half8 __attribute__((ext_vector_type(8)));
typedef float floatx4 __attribute__((ext_vector_type(4)));

__device__ __forceinline__ float fast_tanh(float x) {
  x = fminf(fmaxf(x, -20.f), 20.f);
  const float e = __expf(2.f * x);
  return 1.f - 2.f / (e + 1.f);
}

__device__ __forceinline__ void load_lds16f(const float* g, float* l) {
  __builtin_amdgcn_global_load_lds(
      (const __attribute__((address_space(1))) void*)g,
      (__attribute__((address_space(3))) void*)l, 16, 0, 0);
}

__device__ __forceinline__ void load_lds16h(const _Float16* g, _Float16* l) {
  __builtin_amdgcn_global_load_lds(
      (const __attribute__((address_space(1))) void*)g,
      (__attribute__((address_space(3))) void*)l, 16, 0, 0);
}

// ---------------- prep: W1->w1t | projq | zero context+scores --------------
__global__ __launch_bounds__(256) void prep_fused(
    const float* __restrict__ W1, const float* __restrict__ query,
    const float* __restrict__ W2, const float* __restrict__ b2,
    _Float16* __restrict__ w1t, float* __restrict__ projq,
    float* __restrict__ scores, float* __restrict__ context) {
  __shared__ float sh[64 * 65];
  const int bx = blockIdx.x;
  const int tid = threadIdx.x;
  if (bx < 64) {
    const int t = bx;
    const int k0 = (t >> 3) * 64, u0 = (t & 7) * 64;
    float(*sm)[65] = (float(*)[65])sh;
    const int lu = tid & 63;
    const int g = tid >> 6;
#pragma unroll
    for (int i = 0; i < 16; ++i) {
      const int row = g * 16 + i;
      sm[row][lu] = W1[(long)(k0 + row) * U_ + u0 + lu];
    }
    __syncthreads();
#pragma unroll
    for (int i = 0; i < 16; ++i) {
      const int row = g * 16 + i;
      w1t[(long)(u0 + row) * D_ + k0 + lu] = (_Float16)sm[lu][row];
    }
  } else {
    const int t = bx - 64;  // [0,64)
    const int gid = t * 256 + tid;
    context[gid] = 0.f;                                        // 16384 floats
    ((float4*)scores)[gid] = make_float4(0.f, 0.f, 0.f, 0.f);  // 65536 floats
    const int b = t >> 1;
    const int u = (t & 1) * 256 + tid;
    for (int d = tid; d < D_; d += 256) sh[d] = query[b * D_ + d];
    __syncthreads();
    float acc = 0.f;
#pragma unroll 8
    for (int d = 0; d < D_; ++d) acc += sh[d] * W2[d * U_ + u];
    projq[b * U_ + u] = acc + b2[u];
  }
}

// ---------------- scores: fused fp32-read MFMA, 64m x 128u per block -------
// Grid 4096 blocks (1024 m-tiles x 4 u-tiles, u-minor after XCD swizzle),
// 256 threads = 4 waves (2m x 2u); wave = 32m x 64u via 2x4 MFMA grid,
// acc[2][4] = 32 VGPRs. launch_bounds(256,4) -> 4 blocks/CU.
// A: values fp32 -> LDS [2][64][32] via global_load_lds, dbuf, source-side
//    XOR swizzle slot = chunk^(r&7). Frags: 2x float4 + in-reg cvt (RTE).
// B: w1t f16 -> LDS [2][128][32], dbuf, slot = chunk^((r>>1)&3) (2-way).
// Frag layouts (verified r2-r6): A[m=lane&15][k=(lane>>4)*8+j],
// B[k=(lane>>4)*8+j][n=lane&15], C[row=(lane>>4)*4+reg][col=lane&15].
// Simple loop: issue DMA(t+1), frag ds_reads(t), 8 MFMA, __syncthreads.
__global__ __launch_bounds__(256, 4) void score_fused(
    const float* __restrict__ values, const _Float16* __restrict__ w1t,
    const float* __restrict__ b1, const float* __restrict__ projq,
    const float* __restrict__ V, float* __restrict__ scores) {
  // XCD-chunk swizzle: 4096 wgs, 8 XCDs, 512/chunk; u-minor within chunk
  // (the 4 u-variants of an m-tile differ in bx bits 3-4 -> same XCD).
  const int wgid = (blockIdx.x & 7) * 512 + (blockIdx.x >> 3);
  const int mt = wgid >> 2;        // 0..1023
  const int u0 = (wgid & 3) * 128;
  const int m0 = mt * 64;
  const int b = m0 >> 11;          // 2048 rows per batch
  const int tid = threadIdx.x;
  const int lane = tid & 63;
  const int w = tid >> 6;          // 0..3
  const int wm = (w & 1) * 32;     // m-half of 64
  const int wuL = (w >> 1) * 64;   // u-half of 128 (local)
  const int ln = lane & 15;
  const int lq = lane >> 4;

  __shared__ alignas(16) float As[2][64 * 32];      // 16 KB dbuf
  __shared__ alignas(16) _Float16 Bs[2][128 * 32];  // 16 KB dbuf
  __shared__ float red[2][64];                      // 512 B

  // A-DMA: wave w stages rows [16w,16w+16), 2 instrs of 8 rows.
  // lane l -> row +(l>>3), LDS slot l&7; source chunk (l&7)^(l>>3).
  const int dr = lane >> 3;
  const int dc = (lane & 7) ^ dr;
  const float* gA[2];
#pragma unroll
  for (int j = 0; j < 2; ++j) {
    const int r = w * 16 + j * 8 + dr;
    gA[j] = values + (long)(m0 + r) * D_ + dc * 4;
  }

  // B-DMA: wave w stages rows [32w,32w+32), 2 instrs of 16 rows.
  // lane l -> row +(l>>2), LDS slot l&3; source chunk (l&3)^((l>>3)&3).
  const int br = lane >> 2;
  const int bc = (lane & 3) ^ ((lane >> 3) & 3);
  const _Float16* gB[2];
#pragma unroll
  for (int i = 0; i < 2; ++i) {
    const int r = w * 32 + i * 16 + br;
    gB[i] = w1t + (long)(u0 + r) * D_ + bc * 8;
  }

  floatx4 acc[2][4] = {};

  // prologue: stage k-step 0 into buf 0
#pragma unroll
  for (int j = 0; j < 2; ++j)
    load_lds16f(gA[j], &As[0][(w * 16 + j * 8) * 32]);
#pragma unroll
  for (int i = 0; i < 2; ++i)
    load_lds16h(gB[i], &Bs[0][(w * 32 + i * 16) * 32]);
  __syncthreads();

  for (int t = 0; t < 16; ++t) {
    const int p = t & 1;
    if (t < 15) {  // DMA(t+1) into other buffers, in flight through MFMAs
#pragma unroll
      for (int j = 0; j < 2; ++j)
        load_lds16f(gA[j] + (t + 1) * 32, &As[p ^ 1][(w * 16 + j * 8) * 32]);
#pragma unroll
      for (int i = 0; i < 2; ++i)
        load_lds16h(gB[i] + (t + 1) * 32, &Bs[p ^ 1][(w * 32 + i * 16) * 32]);
    }
    half8 bf[4];
#pragma unroll
    for (int ni = 0; ni < 4; ++ni) {
      const int r = wuL + ni * 16 + ln;
      bf[ni] = *(const half8*)&Bs[p][r * 32 + ((lq ^ ((r >> 1) & 3)) * 8)];
    }
    half8 af[2];
#pragma unroll
    for (int mi = 0; mi < 2; ++mi) {
      const int r = wm + mi * 16 + ln;
      const float* row = &As[p][r * 32];
      const float4 lo = *(const float4*)(row + (((2 * lq) ^ (r & 7)) * 4));
      const float4 hi = *(const float4*)(row + (((2 * lq + 1) ^ (r & 7)) * 4));
      af[mi] = half8{(_Float16)lo.x, (_Float16)lo.y, (_Float16)lo.z,
                     (_Float16)lo.w, (_Float16)hi.x, (_Float16)hi.y,
                     (_Float16)hi.z, (_Float16)hi.w};
    }
#pragma unroll
    for (int mi = 0; mi < 2; ++mi)
#pragma unroll
      for (int ni = 0; ni < 4; ++ni)
        acc[mi][ni] = __builtin_amdgcn_mfma_f32_16x16x32_f16(
            af[mi], bf[ni], acc[mi][ni], 0, 0, 0);
    __syncthreads();
  }

  // Epilogue: partial row scores over this block's 128 u -> atomicAdd.
  float pre[4], vv[4];
#pragma unroll
  for (int ni = 0; ni < 4; ++ni) {
    const int u = u0 + wuL + ni * 16 + ln;
    pre[ni] = b1[u] + projq[b * U_ + u];
    vv[ni] = V[u];
  }
#pragma unroll
  for (int mi = 0; mi < 2; ++mi) {
#pragma unroll
    for (int r = 0; r < 4; ++r) {
      float t = 0.f;
#pragma unroll
      for (int ni = 0; ni < 4; ++ni)
        t += fast_tanh(acc[mi][ni][r] + pre[ni]) * vv[ni];
      t += __shfl_xor(t, 1);
      t += __shfl_xor(t, 2);
      t += __shfl_xor(t, 4);
      t += __shfl_xor(t, 8);
      if (ln == 0) red[w >> 1][wm + mi * 16 + lq * 4 + r] = t;
    }
  }
  __syncthreads();
  if (tid < 64) atomicAdd(scores + m0 + tid, red[0][tid] + red[1][tid]);
}

// ---------------- fused softmax + context ----------------
__global__ __launch_bounds__(256) void softmax_context_kernel(
    const float* __restrict__ scores, const float* __restrict__ values,
    float* __restrict__ weights, float* __restrict__ context) {
  const int b = blockIdx.x;
  const int t0 = blockIdx.y * 64;
  const int tid = threadIdx.x;

  // full-batch softmax stats
  float v[8];
  float mx = -INFINITY;
#pragma unroll
  for (int i = 0; i < 8; ++i) {
    v[i] = scores[b * T_ + i * 256 + tid];
    mx = fmaxf(mx, v[i]);
  }
#pragma unroll
  for (int off = 32; off > 0; off >>= 1) mx = fmaxf(mx, __shfl_down(mx, off));
  __shared__ float sm[4], ss[4];
  if ((tid & 63) == 0) sm[tid >> 6] = mx;
  __syncthreads();
  mx = fmaxf(fmaxf(sm[0], sm[1]), fmaxf(sm[2], sm[3]));
  float sum = 0.f;
#pragma unroll
  for (int i = 0; i < 8; ++i) sum += __expf(v[i] - mx);
#pragma unroll
  for (int off = 32; off > 0; off >>= 1) sum += __shfl_down(sum, off);
  if ((tid & 63) == 0) ss[tid >> 6] = sum;
  __syncthreads();
  const float inv = 1.f / (ss[0] + ss[1] + ss[2] + ss[3]);

  // weights for our 64 rows
  __shared__ float wsh[64];
  if (tid < 64) {
    const float ww = __expf(scores[b * T_ + t0 + tid] - mx) * inv;
    wsh[tid] = ww;
    weights[b * T_ + t0 + tid] = ww;
  }
  __syncthreads();

  // context partial
  const int g = tid >> 7;
  const int dx = tid & 127;
  __shared__ float4 part[128];
  float4 acc = make_float4(0.f, 0.f, 0.f, 0.f);
  const float4* vp = (const float4*)(values + (long)(b * T_ + t0 + g) * D_) + dx;
#pragma unroll 4
  for (int t = 0; t < 32; ++t) {
    const float4 x = vp[(long)(2 * t) * (D_ / 4)];
    const float ww = wsh[2 * t + g];
    acc.x += ww * x.x; acc.y += ww * x.y; acc.z += ww * x.z; acc.w += ww * x.w;
  }
  if (g == 0) part[dx] = acc;
  __syncthreads();
  if (g == 1) {
    const float4 p = part[dx];
    atomicAdd(&context[b * D_ + dx * 4 + 0], acc.x + p.x);
    atomicAdd(&context[b * D_ + dx * 4 + 1], acc.y + p.y);
    atomicAdd(&context[b * D_ + dx * 4 + 2], acc.z + p.z);
    atomicAdd(&context[b * D_ + dx * 4 + 3], acc.w + p.w);
  }
}

extern "C" void kernel_launch(void* const* d_in, const int* in_sizes, int n_in,
                              void* d_out, int out_size, void* d_ws, size_t ws_size,
                              hipStream_t stream) {
  const float* values = (const float*)d_in[0];
  const float* query = (const float*)d_in[1];
  const float* W1 = (const float*)d_in[2];
  const float* b1 = (const float*)d_in[3];
  const float* W2 = (const float*)d_in[4];
  const float* b2 = (const float*)d_in[5];
  const float* V = (const float*)d_in[6];
  // d_in[7] = bV: unused — softmax is shift-invariant.

  float* out = (float*)d_out;
  float* context = out;            // [32,512]
  float* weights = out + B_ * D_;  // [32,2048]
  float* projq = (float*)d_ws;                                // 64KB
  float* scores = projq + B_ * U_;                            // 256KB
  _Float16* w1t = (_Float16*)((char*)d_ws + 65536 + 262144);  // 512KB

  prep_fused<<<128, 256, 0, stream>>>(W1, query, W2, b2, w1t, projq, scores,
                                      context);
  score_fused<<<4096, 256, 0, stream>>>(values, w1t, b1, projq, V, scores);
  softmax_context_kernel<<<dim3(B_, T_ / 64), 256, 0, stream>>>(
      scores, values, weights, context);
}

// Round 7
// 328.992 us; speedup vs baseline: 1.0069x; 1.0069x over previous
//
#include <hip/hip_runtime.h>
#include <math.h>

// Bahdanau attention, B=32, T=2048, D=512, U=512, fp32 in/out.
// Round 14: m97-geometry score tile. r13's 64x128 tile had only 8 MFMA/wave
// per barrier drain (fixed ~600-900cy vmcnt(0) cost per step) -> 65k drains,
// convoying, MfmaUtil 10%. Now 128m x 128u, BK=32, 4 waves, wave = 64x64 via
// 4x4 accs = 16 MFMA/wave/step (2x work per drain, half the block-rows),
// LDS 50KB -> 3 blocks/CU (launch_bounds(256,3)). All verified formulas
// (fp32-A in-flight cvt, XOR swizzles, frag layouts, epilogue) unchanged.
// Grid 2048 = 512 m-tiles x 4 u-strips, XCD-grouped u-minor.

#define B_ 32
#define T_ 2048
#define D_ 512
#define U_ 512
#define M_ (B_ * T_)

typedef _Float16 half8 __attribute__((ext_vector_type(8)));
typedef float floatx4 __attribute__((ext_vector_type(4)));

__device__ __forceinline__ float fast_tanh(float x) {
  x = fminf(fmaxf(x, -20.f), 20.f);
  const float e = __expf(2.f * x);
  return 1.f - 2.f / (e + 1.f);
}

__device__ __forceinline__ void load_lds16f(const float* g, float* l) {
  __builtin_amdgcn_global_load_lds(
      (const __attribute__((address_space(1))) void*)g,
      (__attribute__((address_space(3))) void*)l, 16, 0, 0);
}

__device__ __forceinline__ void load_lds16h(const _Float16* g, _Float16* l) {
  __builtin_amdgcn_global_load_lds(
      (const __attribute__((address_space(1))) void*)g,
      (__attribute__((address_space(3))) void*)l, 16, 0, 0);
}

// ---------------- prep: W1->w1t | projq | zero context+scores --------------
__global__ __launch_bounds__(256) void prep_fused(
    const float* __restrict__ W1, const float* __restrict__ query,
    const float* __restrict__ W2, const float* __restrict__ b2,
    _Float16* __restrict__ w1t, float* __restrict__ projq,
    float* __restrict__ scores, float* __restrict__ context) {
  __shared__ float sh[64 * 65];
  const int bx = blockIdx.x;
  const int tid = threadIdx.x;
  if (bx < 64) {
    const int t = bx;
    const int k0 = (t >> 3) * 64, u0 = (t & 7) * 64;
    float(*sm)[65] = (float(*)[65])sh;
    const int lu = tid & 63;
    const int g = tid >> 6;
#pragma unroll
    for (int i = 0; i < 16; ++i) {
      const int row = g * 16 + i;
      sm[row][lu] = W1[(long)(k0 + row) * U_ + u0 + lu];
    }
    __syncthreads();
#pragma unroll
    for (int i = 0; i < 16; ++i) {
      const int row = g * 16 + i;
      w1t[(long)(u0 + row) * D_ + k0 + lu] = (_Float16)sm[lu][row];
    }
  } else {
    const int t = bx - 64;  // [0,64)
    const int gid = t * 256 + tid;
    context[gid] = 0.f;                                        // 16384 floats
    ((float4*)scores)[gid] = make_float4(0.f, 0.f, 0.f, 0.f);  // 65536 floats
    const int b = t >> 1;
    const int u = (t & 1) * 256 + tid;
    for (int d = tid; d < D_; d += 256) sh[d] = query[b * D_ + d];
    __syncthreads();
    float acc = 0.f;
#pragma unroll 8
    for (int d = 0; d < D_; ++d) acc += sh[d] * W2[d * U_ + u];
    projq[b * U_ + u] = acc + b2[u];
  }
}

// ---------------- scores: fused fp32-read MFMA, 128m x 128u per block ------
// Grid 2048 blocks (512 m-tiles x 4 u-strips, u-minor after XCD swizzle),
// 256 threads = 4 waves (2m x 2u); wave = 64m x 64u via 4x4 MFMA accs
// (64 VGPR). launch_bounds(256,3) -> 3 blocks/CU (LDS 50KB).
// A: values fp32 -> LDS [2][128][32] via global_load_lds (4 instr/wave/step),
//    source-side XOR swizzle slot = chunk^(r&7). Frag: 2 float4 + cvt.
// B: w1t f16 -> LDS [2][128][32] (2 instr/wave/step), slot = chunk^((r>>1)&3).
// Frag layouts (verified r2-r6): A[m=lane&15][k=(lane>>4)*8+j],
// B[k=(lane>>4)*8+j][n=lane&15], C[row=(lane>>4)*4+reg][col=lane&15].
// Loop: issue DMA(t+1), frag ds_reads(t), 16 MFMA/wave, __syncthreads.
__global__ __launch_bounds__(256, 3) void score_fused(
    const float* __restrict__ values, const _Float16* __restrict__ w1t,
    const float* __restrict__ b1, const float* __restrict__ projq,
    const float* __restrict__ V, float* __restrict__ scores) {
  // XCD-chunk swizzle: 2048 wgs, 8 XCDs, 256/chunk; u-minor within chunk
  // (4 u-strips of an m-tile land consecutively on one XCD -> L2 reuse).
  const int wgid = (blockIdx.x & 7) * 256 + (blockIdx.x >> 3);
  const int mt = wgid >> 2;        // 0..511
  const int u0 = (wgid & 3) * 128;
  const int m0 = mt * 128;
  const int b = m0 >> 11;          // 2048 rows per batch
  const int tid = threadIdx.x;
  const int lane = tid & 63;
  const int w = tid >> 6;          // 0..3
  const int wm = (w & 1) * 64;     // m-half of 128
  const int wu = (w >> 1) * 64;    // u-half of 128 (local)
  const int ln = lane & 15;
  const int lq = lane >> 4;

  __shared__ alignas(16) float As[2][128 * 32];     // 32 KB dbuf
  __shared__ alignas(16) _Float16 Bs[2][128 * 32];  // 16 KB dbuf
  __shared__ float red[2][128];                     // 1 KB

  // A-DMA: wave w stages rows [32w,32w+32), 4 instrs of 8 rows.
  // lane l -> row +(l>>3), LDS slot l&7; source chunk (l&7)^(l>>3).
  const int dr = lane >> 3;
  const int dc = (lane & 7) ^ dr;
  const float* gA[4];
#pragma unroll
  for (int j = 0; j < 4; ++j) {
    const int r = w * 32 + j * 8 + dr;
    gA[j] = values + (long)(m0 + r) * D_ + dc * 4;
  }

  // B-DMA: wave w stages rows [32w,32w+32), 2 instrs of 16 rows.
  // lane l -> row +(l>>2), LDS slot l&3; source chunk (l&3)^((l>>3)&3).
  const int br = lane >> 2;
  const int bc = (lane & 3) ^ ((lane >> 3) & 3);
  const _Float16* gB[2];
#pragma unroll
  for (int i = 0; i < 2; ++i) {
    const int r = w * 32 + i * 16 + br;
    gB[i] = w1t + (long)(u0 + r) * D_ + bc * 8;
  }

  floatx4 acc[4][4] = {};

  // prologue: stage k-step 0 into buf 0
#pragma unroll
  for (int j = 0; j < 4; ++j)
    load_lds16f(gA[j], &As[0][(w * 32 + j * 8) * 32]);
#pragma unroll
  for (int i = 0; i < 2; ++i)
    load_lds16h(gB[i], &Bs[0][(w * 32 + i * 16) * 32]);
  __syncthreads();

  for (int t = 0; t < 16; ++t) {
    const int p = t & 1;
    if (t < 15) {  // DMA(t+1) into other buffers, in flight through MFMAs
#pragma unroll
      for (int j = 0; j < 4; ++j)
        load_lds16f(gA[j] + (t + 1) * 32, &As[p ^ 1][(w * 32 + j * 8) * 32]);
#pragma unroll
      for (int i = 0; i < 2; ++i)
        load_lds16h(gB[i] + (t + 1) * 32, &Bs[p ^ 1][(w * 32 + i * 16) * 32]);
    }
    half8 bf[4];
#pragma unroll
    for (int ni = 0; ni < 4; ++ni) {
      const int r = wu + ni * 16 + ln;
      bf[ni] = *(const half8*)&Bs[p][r * 32 + ((lq ^ ((r >> 1) & 3)) * 8)];
    }
    half8 af[4];
#pragma unroll
    for (int mi = 0; mi < 4; ++mi) {
      const int r = wm + mi * 16 + ln;
      const float* row = &As[p][r * 32];
      const float4 lo = *(const float4*)(row + (((2 * lq) ^ (r & 7)) * 4));
      const float4 hi = *(const float4*)(row + (((2 * lq + 1) ^ (r & 7)) * 4));
      af[mi] = half8{(_Float16)lo.x, (_Float16)lo.y, (_Float16)lo.z,
                     (_Float16)lo.w, (_Float16)hi.x, (_Float16)hi.y,
                     (_Float16)hi.z, (_Float16)hi.w};
    }
#pragma unroll
    for (int mi = 0; mi < 4; ++mi)
#pragma unroll
      for (int ni = 0; ni < 4; ++ni)
        acc[mi][ni] = __builtin_amdgcn_mfma_f32_16x16x32_f16(
            af[mi], bf[ni], acc[mi][ni], 0, 0, 0);
    __syncthreads();
  }

  // Epilogue: partial row scores over this block's 128 u -> atomicAdd.
  float pre[4], vv[4];
#pragma unroll
  for (int ni = 0; ni < 4; ++ni) {
    const int u = u0 + wu + ni * 16 + ln;
    pre[ni] = b1[u] + projq[b * U_ + u];
    vv[ni] = V[u];
  }
#pragma unroll
  for (int mi = 0; mi < 4; ++mi) {
#pragma unroll
    for (int r = 0; r < 4; ++r) {
      float t = 0.f;
#pragma unroll
      for (int ni = 0; ni < 4; ++ni)
        t += fast_tanh(acc[mi][ni][r] + pre[ni]) * vv[ni];
      t += __shfl_xor(t, 1);
      t += __shfl_xor(t, 2);
      t += __shfl_xor(t, 4);
      t += __shfl_xor(t, 8);
      if (ln == 0) red[w >> 1][wm + mi * 16 + lq * 4 + r] = t;
    }
  }
  __syncthreads();
  if (tid < 128) atomicAdd(scores + m0 + tid, red[0][tid] + red[1][tid]);
}

// ---------------- fused softmax + context ----------------
__global__ __launch_bounds__(256) void softmax_context_kernel(
    const float* __restrict__ scores, const float* __restrict__ values,
    float* __restrict__ weights, float* __restrict__ context) {
  const int b = blockIdx.x;
  const int t0 = blockIdx.y * 64;
  const int tid = threadIdx.x;

  // full-batch softmax stats
  float v[8];
  float mx = -INFINITY;
#pragma unroll
  for (int i = 0; i < 8; ++i) {
    v[i] = scores[b * T_ + i * 256 + tid];
    mx = fmaxf(mx, v[i]);
  }
#pragma unroll
  for (int off = 32; off > 0; off >>= 1) mx = fmaxf(mx, __shfl_down(mx, off));
  __shared__ float sm[4], ss[4];
  if ((tid & 63) == 0) sm[tid >> 6] = mx;
  __syncthreads();
  mx = fmaxf(fmaxf(sm[0], sm[1]), fmaxf(sm[2], sm[3]));
  float sum = 0.f;
#pragma unroll
  for (int i = 0; i < 8; ++i) sum += __expf(v[i] - mx);
#pragma unroll
  for (int off = 32; off > 0; off >>= 1) sum += __shfl_down(sum, off);
  if ((tid & 63) == 0) ss[tid >> 6] = sum;
  __syncthreads();
  const float inv = 1.f / (ss[0] + ss[1] + ss[2] + ss[3]);

  // weights for our 64 rows
  __shared__ float wsh[64];
  if (tid < 64) {
    const float ww = __expf(scores[b * T_ + t0 + tid] - mx) * inv;
    wsh[tid] = ww;
    weights[b * T_ + t0 + tid] = ww;
  }
  __syncthreads();

  // context partial
  const int g = tid >> 7;
  const int dx = tid & 127;
  __shared__ float4 part[128];
  float4 acc = make_float4(0.f, 0.f, 0.f, 0.f);
  const float4* vp = (const float4*)(values + (long)(b * T_ + t0 + g) * D_) + dx;
#pragma unroll 4
  for (int t = 0; t < 32; ++t) {
    const float4 x = vp[(long)(2 * t) * (D_ / 4)];
    const float ww = wsh[2 * t + g];
    acc.x += ww * x.x; acc.y += ww * x.y; acc.z += ww * x.z; acc.w += ww * x.w;
  }
  if (g == 0) part[dx] = acc;
  __syncthreads();
  if (g == 1) {
    const float4 p = part[dx];
    atomicAdd(&context[b * D_ + dx * 4 + 0], acc.x + p.x);
    atomicAdd(&context[b * D_ + dx * 4 + 1], acc.y + p.y);
    atomicAdd(&context[b * D_ + dx * 4 + 2], acc.z + p.z);
    atomicAdd(&context[b * D_ + dx * 4 + 3], acc.w + p.w);
  }
}

extern "C" void kernel_launch(void* const* d_in, const int* in_sizes, int n_in,
                              void* d_out, int out_size, void* d_ws, size_t ws_size,
                              hipStream_t stream) {
  const float* values = (const float*)d_in[0];
  const float* query = (const float*)d_in[1];
  const float* W1 = (const float*)d_in[2];
  const float* b1 = (const float*)d_in[3];
  const float* W2 = (const float*)d_in[4];
  const float* b2 = (const float*)d_in[5];
  const float* V = (const float*)d_in[6];
  // d_in[7] = bV: unused — softmax is shift-invariant.

  float* out = (float*)d_out;
  float* context = out;            // [32,512]
  float* weights = out + B_ * D_;  // [32,2048]
  float* projq = (float*)d_ws;                                // 64KB
  float* scores = projq + B_ * U_;                            // 256KB
  _Float16* w1t = (_Float16*)((char*)d_ws + 65536 + 262144);  // 512KB

  prep_fused<<<128, 256, 0, stream>>>(W1, query, W2, b2, w1t, projq, scores,
                                      context);
  score_fused<<<2048, 256, 0, stream>>>(values, w1t, b1, projq, V, scores);
  softmax_context_kernel<<<dim3(B_, T_ / 64), 256, 0, stream>>>(
      scores, values, weights, context);
}

// Round 8
// 298.908 us; speedup vs baseline: 1.1082x; 1.1006x over previous
//
#include <hip/hip_runtime.h>
#include <math.h>

// Bahdanau attention, B=32, T=2048, D=512, U=512, fp32 in/out.
// Round 15: (1) restore r10's score_fused verbatim (96us, best measured;
// rounds 11-14 were net-negative churn on it). (2) rewrite softmax_context:
// 128 rows/block (512 blocks, half the atomics), context loop unrolled 8
// (8 independent float4 loads in flight -> hides HBM latency on the 128MB
// values stream). Stats recompute per block unchanged (deterministic).

#define B_ 32
#define T_ 2048
#define D_ 512
#define U_ 512
#define M_ (B_ * T_)

typedef _Float16 half8 __attribute__((ext_vector_type(8)));
typedef float floatx4 __attribute__((ext_vector_type(4)));

__device__ __forceinline__ float fast_tanh(float x) {
  x = fminf(fmaxf(x, -20.f), 20.f);
  const float e = __expf(2.f * x);
  return 1.f - 2.f / (e + 1.f);
}

__device__ __forceinline__ void load_lds16f(const float* g, float* l) {
  __builtin_amdgcn_global_load_lds(
      (const __attribute__((address_space(1))) void*)g,
      (__attribute__((address_space(3))) void*)l, 16, 0, 0);
}

__device__ __forceinline__ void load_lds16h(const _Float16* g, _Float16* l) {
  __builtin_amdgcn_global_load_lds(
      (const __attribute__((address_space(1))) void*)g,
      (__attribute__((address_space(3))) void*)l, 16, 0, 0);
}

// ---------------- prep: W1->w1t | projq | zero context ---------------------
// blocks [0,64): W1 [k][u] -> w1t [u][k] f16 (64 x 64x64 tiles)
// blocks [64,128): projq = query@W2+b2; zero context
__global__ __launch_bounds__(256) void prep_fused(
    const float* __restrict__ W1, const float* __restrict__ query,
    const float* __restrict__ W2, const float* __restrict__ b2,
    _Float16* __restrict__ w1t, float* __restrict__ projq,
    float* __restrict__ context) {
  __shared__ float sh[64 * 65];
  const int bx = blockIdx.x;
  const int tid = threadIdx.x;
  if (bx < 64) {
    const int t = bx;
    const int k0 = (t >> 3) * 64, u0 = (t & 7) * 64;
    float(*sm)[65] = (float(*)[65])sh;
    const int lu = tid & 63;
    const int g = tid >> 6;
#pragma unroll
    for (int i = 0; i < 16; ++i) {
      const int row = g * 16 + i;
      sm[row][lu] = W1[(long)(k0 + row) * U_ + u0 + lu];
    }
    __syncthreads();
#pragma unroll
    for (int i = 0; i < 16; ++i) {
      const int row = g * 16 + i;
      w1t[(long)(u0 + row) * D_ + k0 + lu] = (_Float16)sm[lu][row];
    }
  } else {
    const int t = bx - 64;  // [0,64)
    const int gid = t * 256 + tid;
    context[gid] = 0.f;  // 16384 floats
    const int b = t >> 1;
    const int u = (t & 1) * 256 + tid;
    for (int d = tid; d < D_; d += 256) sh[d] = query[b * D_ + d];
    __syncthreads();
    float acc = 0.f;
#pragma unroll 8
    for (int d = 0; d < D_; ++d) acc += sh[d] * W2[d * U_ + u];
    projq[b * U_ + u] = acc + b2[u];
  }
}

// ---------------- scores: fused fp32-read MFMA, 128m x 512u per block ------
// (r10 structure, verbatim: best measured at 96us.)
// Grid M/128 = 512 blocks, 512 threads = 8 waves (2m x 4u).
// Wave = 64m x 128u via 4x8 grid of 16x16x32 MFMA (acc 128 regs).
// A: values fp32 -> LDS [128][32] f32 via global_load_lds, double-buffered,
//    source-side XOR chunk swizzle (slot s of row r holds chunk s^(r&7)).
//    Fragments read as 2x float4 + in-register cvt to half8 (RTE).
// B: w1t [u][k] f16 -> LDS [512][32] halves via global_load_lds, double-
//    buffered, source-side swizzle (slot s of row r holds chunk s^(r&3)).
// Frag layouts (verified r2-r6): A[m=lane&15][k=(lane>>4)*8+j],
// B[k=(lane>>4)*8+j][n=lane&15], C[row=(lane>>4)*4+reg][col=lane&15].
__global__ __launch_bounds__(512, 1) void score_fused(
    const float* __restrict__ values, const _Float16* __restrict__ w1t,
    const float* __restrict__ b1, const float* __restrict__ projq,
    const float* __restrict__ V, float* __restrict__ scores) {
  const int m0 = blockIdx.x * 128;
  const int b = blockIdx.x >> 4;  // 2048/128 = 16 row-blocks per batch
  const int tid = threadIdx.x;
  const int lane = tid & 63;
  const int w = tid >> 6;          // 0..7
  const int wm = (w & 1) * 64;     // m-half
  const int wu = (w >> 1) * 128;   // u-quarter
  const int ln = lane & 15;
  const int lq = lane >> 4;

  __shared__ alignas(16) float As[2][128 * 32];     // 32 KB dbuf
  __shared__ alignas(16) _Float16 Bs[2][512 * 32];  // 64 KB dbuf
  __shared__ float red[4][128];                     // 2 KB

  // A-DMA: wave w stages rows [16w,16w+16) per step, 2 instrs of 8 rows.
  const int dr = lane >> 3;
  const int dc = (lane & 7) ^ dr;
  const float* gA[2];
#pragma unroll
  for (int j = 0; j < 2; ++j) {
    const int r = w * 16 + j * 8 + dr;
    gA[j] = values + (long)(m0 + r) * D_ + dc * 4;
  }

  // B-DMA: wave w stages rows [64w,64w+64) per step, 4 instrs of 16 rows.
  const int br = lane >> 2;
  const int bc = (lane & 3) ^ (br & 3);
  const _Float16* gB[4];
#pragma unroll
  for (int i = 0; i < 4; ++i) {
    const int r = w * 64 + i * 16 + br;
    gB[i] = w1t + (long)r * D_ + bc * 8;
  }

  floatx4 acc[4][8] = {};

  // prologue: stage k-step 0 into buf 0
#pragma unroll
  for (int j = 0; j < 2; ++j)
    load_lds16f(gA[j], &As[0][(w * 16 + j * 8) * 32]);
#pragma unroll
  for (int i = 0; i < 4; ++i)
    load_lds16h(gB[i], &Bs[0][(w * 64 + i * 16) * 32]);
  __syncthreads();

  for (int t = 0; t < 16; ++t) {
    const int p = t & 1;
    if (t < 15) {
#pragma unroll
      for (int j = 0; j < 2; ++j)
        load_lds16f(gA[j] + (t + 1) * 32, &As[p ^ 1][(w * 16 + j * 8) * 32]);
#pragma unroll
      for (int i = 0; i < 4; ++i)
        load_lds16h(gB[i] + (t + 1) * 32, &Bs[p ^ 1][(w * 64 + i * 16) * 32]);
    }
    half8 bf[8];
#pragma unroll
    for (int ni = 0; ni < 8; ++ni) {
      const int r = wu + ni * 16 + ln;
      bf[ni] = *(const half8*)&Bs[p][r * 32 + ((lq ^ (ln & 3)) * 8)];
    }
    half8 af[4];
#pragma unroll
    for (int mi = 0; mi < 4; ++mi) {
      const int r = wm + mi * 16 + ln;
      const float* row = &As[p][r * 32];
      const float4 lo = *(const float4*)(row + (((2 * lq) ^ (r & 7)) * 4));
      const float4 hi = *(const float4*)(row + (((2 * lq + 1) ^ (r & 7)) * 4));
      af[mi] = half8{(_Float16)lo.x, (_Float16)lo.y, (_Float16)lo.z,
                     (_Float16)lo.w, (_Float16)hi.x, (_Float16)hi.y,
                     (_Float16)hi.z, (_Float16)hi.w};
    }
#pragma unroll
    for (int mi = 0; mi < 4; ++mi)
#pragma unroll
      for (int ni = 0; ni < 8; ++ni)
        acc[mi][ni] = __builtin_amdgcn_mfma_f32_16x16x32_f16(
            af[mi], bf[ni], acc[mi][ni], 0, 0, 0);
    __syncthreads();
  }

  // Epilogue: full row scores (each block owns its 128 rows exclusively).
  float pre[8], vv[8];
#pragma unroll
  for (int ni = 0; ni < 8; ++ni) {
    const int u = wu + ni * 16 + ln;
    pre[ni] = b1[u] + projq[b * U_ + u];
    vv[ni] = V[u];
  }
#pragma unroll
  for (int mi = 0; mi < 4; ++mi) {
#pragma unroll
    for (int r = 0; r < 4; ++r) {
      float t = 0.f;
#pragma unroll
      for (int ni = 0; ni < 8; ++ni)
        t += fast_tanh(acc[mi][ni][r] + pre[ni]) * vv[ni];
      t += __shfl_xor(t, 1);
      t += __shfl_xor(t, 2);
      t += __shfl_xor(t, 4);
      t += __shfl_xor(t, 8);
      if (ln == 0) red[w >> 1][wm + mi * 16 + lq * 4 + r] = t;
    }
  }
  __syncthreads();
  if (tid < 128)
    scores[m0 + tid] =
        red[0][tid] + red[1][tid] + red[2][tid] + red[3][tid];
}

// ---------------- fused softmax + context ----------------
// Grid (B, T/128) = 512 blocks. Every block recomputes batch-b softmax stats
// from scores (deterministic), writes its 128-row weight slice, accumulates
// its context partial via atomics. Context loop 8-deep unrolled: 8
// independent float4 loads in flight per thread hide HBM latency.
__global__ __launch_bounds__(256) void softmax_context_kernel(
    const float* __restrict__ scores, const float* __restrict__ values,
    float* __restrict__ weights, float* __restrict__ context) {
  const int b = blockIdx.x;
  const int t0 = blockIdx.y * 128;
  const int tid = threadIdx.x;

  // full-batch softmax stats
  float v[8];
  float mx = -INFINITY;
#pragma unroll
  for (int i = 0; i < 8; ++i) {
    v[i] = scores[b * T_ + i * 256 + tid];
    mx = fmaxf(mx, v[i]);
  }
#pragma unroll
  for (int off = 32; off > 0; off >>= 1) mx = fmaxf(mx, __shfl_down(mx, off));
  __shared__ float sm[4], ss[4];
  if ((tid & 63) == 0) sm[tid >> 6] = mx;
  __syncthreads();
  mx = fmaxf(fmaxf(sm[0], sm[1]), fmaxf(sm[2], sm[3]));
  float sum = 0.f;
#pragma unroll
  for (int i = 0; i < 8; ++i) sum += __expf(v[i] - mx);
#pragma unroll
  for (int off = 32; off > 0; off >>= 1) sum += __shfl_down(sum, off);
  if ((tid & 63) == 0) ss[tid >> 6] = sum;
  __syncthreads();
  const float inv = 1.f / (ss[0] + ss[1] + ss[2] + ss[3]);

  // weights for our 128 rows
  __shared__ float wsh[128];
  if (tid < 128) {
    const float ww = __expf(scores[b * T_ + t0 + tid] - mx) * inv;
    wsh[tid] = ww;
    weights[b * T_ + t0 + tid] = ww;
  }
  __syncthreads();

  // context partial: 128 rows, 2 row-groups x 128 float4-cols.
  const int g = tid >> 7;
  const int dx = tid & 127;
  __shared__ float4 part[128];
  float4 acc = make_float4(0.f, 0.f, 0.f, 0.f);
  const float4* vp = (const float4*)(values + (long)(b * T_ + t0 + g) * D_) + dx;
#pragma unroll 8
  for (int t = 0; t < 64; ++t) {
    const float4 x = vp[(long)(2 * t) * (D_ / 4)];
    const float ww = wsh[2 * t + g];
    acc.x += ww * x.x; acc.y += ww * x.y; acc.z += ww * x.z; acc.w += ww * x.w;
  }
  if (g == 0) part[dx] = acc;
  __syncthreads();
  if (g == 1) {
    const float4 p = part[dx];
    atomicAdd(&context[b * D_ + dx * 4 + 0], acc.x + p.x);
    atomicAdd(&context[b * D_ + dx * 4 + 1], acc.y + p.y);
    atomicAdd(&context[b * D_ + dx * 4 + 2], acc.z + p.z);
    atomicAdd(&context[b * D_ + dx * 4 + 3], acc.w + p.w);
  }
}

extern "C" void kernel_launch(void* const* d_in, const int* in_sizes, int n_in,
                              void* d_out, int out_size, void* d_ws, size_t ws_size,
                              hipStream_t stream) {
  const float* values = (const float*)d_in[0];
  const float* query = (const float*)d_in[1];
  const float* W1 = (const float*)d_in[2];
  const float* b1 = (const float*)d_in[3];
  const float* W2 = (const float*)d_in[4];
  const float* b2 = (const float*)d_in[5];
  const float* V = (const float*)d_in[6];
  // d_in[7] = bV: unused — softmax is shift-invariant.

  float* out = (float*)d_out;
  float* context = out;            // [32,512]
  float* weights = out + B_ * D_;  // [32,2048]
  float* projq = (float*)d_ws;                                // 64KB
  float* scores = projq + B_ * U_;                            // 256KB
  _Float16* w1t = (_Float16*)((char*)d_ws + 65536 + 262144);  // 512KB

  prep_fused<<<128, 256, 0, stream>>>(W1, query, W2, b2, w1t, projq, context);
  score_fused<<<M_ / 128, 512, 0, stream>>>(values, w1t, b1, projq, V, scores);
  softmax_context_kernel<<<dim3(B_, T_ / 128), 256, 0, stream>>>(
      scores, values, weights, context);
}